// Round 7
// baseline (445.472 us; speedup 1.0000x reference)
//
#include <hip/hip_runtime.h>
#include <hip/hip_bf16.h>
#include <math.h>

#define NB 4
#define NS 2048
#define ND 1024
#define NH 16
#define NHD 64
#define NDFF 4096
#define QKS 3072   // packed qkv row stride

typedef __attribute__((ext_vector_type(8))) short bf16x8;
typedef __attribute__((ext_vector_type(4))) float f32x4;
typedef __attribute__((ext_vector_type(16))) float f32x16;
typedef __attribute__((ext_vector_type(4))) short short4v;
typedef __attribute__((ext_vector_type(4))) int i32x4;

static __device__ __forceinline__ short f2b(float f) {
  union { __hip_bfloat16 b; short s; } u;
  u.b = __float2bfloat16(f);
  return u.s;
}

static __device__ __forceinline__ int cvtpk(float lo, float hi_) {
  int r;
  asm("v_cvt_pk_bf16_f32 %0, %1, %2" : "=v"(r) : "v"(lo), "v"(hi_));
  return r;
}

static __device__ __forceinline__ float pairmax(float x) {
  auto r = __builtin_amdgcn_permlane32_swap(__float_as_uint(x), __float_as_uint(x), false, false);
  return fmaxf(__uint_as_float(r[0]), __uint_as_float(r[1]));
}
static __device__ __forceinline__ float pairsum(float x) {
  auto r = __builtin_amdgcn_permlane32_swap(__float_as_uint(x), __float_as_uint(x), false, false);
  return __uint_as_float(r[0]) + __uint_as_float(r[1]);
}

// ---------------- LayerNorm: f32 in -> bf16 out ----------------
__global__ __launch_bounds__(256) void ln_kernel(
    const float* __restrict__ x, const float* __restrict__ g,
    const float* __restrict__ b, short* __restrict__ out) {
  __shared__ float red[8];
  const int row = blockIdx.x;
  const int t = threadIdx.x;
  const float* xr = x + (size_t)row * ND;
  const float4 xv = *(const float4*)(xr + t * 4);
  float s = xv.x + xv.y + xv.z + xv.w;
  float ss = xv.x * xv.x + xv.y * xv.y + xv.z * xv.z + xv.w * xv.w;
#pragma unroll
  for (int m = 32; m >= 1; m >>= 1) {
    s += __shfl_xor(s, m);
    ss += __shfl_xor(ss, m);
  }
  if ((t & 63) == 0) { red[(t >> 6) * 2] = s; red[(t >> 6) * 2 + 1] = ss; }
  __syncthreads();
  s = red[0] + red[2] + red[4] + red[6];
  ss = red[1] + red[3] + red[5] + red[7];
  const float mu = s * (1.0f / ND);
  const float var = ss * (1.0f / ND) - mu * mu;
  const float rs = rsqrtf(var + 1e-5f);
  const float4 gv = *(const float4*)(g + t * 4);
  const float4 bv = *(const float4*)(b + t * 4);
  short o[4];
  o[0] = f2b((xv.x - mu) * rs * gv.x + bv.x);
  o[1] = f2b((xv.y - mu) * rs * gv.y + bv.y);
  o[2] = f2b((xv.z - mu) * rs * gv.z + bv.z);
  o[3] = f2b((xv.w - mu) * rs * gv.w + bv.w);
  *(short4v*)(out + (size_t)row * ND + t * 4) = *(short4v*)o;
}

// ------------- transpose + cast: in f32 (K x N) -> out bf16 (N x K) -------------
__global__ __launch_bounds__(256) void tcast_kernel(
    const float* __restrict__ in, short* __restrict__ out, int K, int N) {
  __shared__ float tile[32][33];
  const int n0 = blockIdx.x * 32, k0 = blockIdx.y * 32;
  const int tx = threadIdx.x & 31, ty = threadIdx.x >> 5;  // 32 x 8
#pragma unroll
  for (int i = 0; i < 32; i += 8)
    tile[ty + i][tx] = in[(size_t)(k0 + ty + i) * N + n0 + tx];
  __syncthreads();
#pragma unroll
  for (int i = 0; i < 32; i += 8)
    out[(size_t)(n0 + ty + i) * K + k0 + tx] = f2b(tile[tx][ty + i]);
}

// ------------- V transpose: packed qkv (v at col 2048) -> vt[b*H+h][d][s] bf16 -------------
__global__ __launch_bounds__(256) void vtrans_kernel(
    const short* __restrict__ in, short* __restrict__ out) {
  __shared__ short tile[64][72];
  const int s0 = blockIdx.x * 64, bh = blockIdx.y;
  const int bb = bh >> 4, hh = bh & 15;
  const int rr = threadIdx.x >> 3, cc = (threadIdx.x & 7) * 8;  // rr 0..31
#pragma unroll
  for (int it = 0; it < 2; ++it) {
    const int r = rr + it * 32;
    *(bf16x8*)&tile[r][cc] =
        *(const bf16x8*)&in[((size_t)(bb * NS + s0 + r)) * QKS + 2048 + hh * NHD + cc];
  }
  __syncthreads();
  const size_t ob = (size_t)bh * NHD * NS;
#pragma unroll
  for (int it = 0; it < 2; ++it) {
    const int d = rr + it * 32;
    short o[8];
#pragma unroll
    for (int j = 0; j < 8; ++j) o[j] = tile[cc + j][d];
    *(bf16x8*)&out[ob + (size_t)d * NS + s0 + cc] = *(bf16x8*)o;
  }
}

__device__ __forceinline__ void gload16(const void* g, void* l) {
  __builtin_amdgcn_global_load_lds(
      (const __attribute__((address_space(1))) unsigned int*)g,
      (__attribute__((address_space(3))) unsigned int*)l, 16, 0, 0);
}

// ====== 4-phase-per-K-step pipelined GEMM: C(256 x BN) = A(MxK) * Bt(NxK)^T ======
// BK=64 split in 2 k-halves. LDS/buffer = units {Ak0,Ak1,Bk0,Bk1}, dbuf.
// Phase (kh,ch): [ds_read frags | stage 1 unit of t+1] bar [16 MFMA setprio] (vmcnt) bar.
// Counted vmcnt proves oldest unit-pair landed; never drains mid-loop.
// EPI: 0 = plain -> bf16; 1 = +res -> f32; 2 = +bias,gelu -> bf16; 3 = +bias+res -> f32
template <int BN, int EPI>
__global__ __launch_bounds__(BN == 256 ? 512 : 256, BN == 256 ? 2 : 1) void gemmp_kernel(
    const short* __restrict__ A, const short* __restrict__ Bt,
    float* __restrict__ Cf, short* __restrict__ Cb,
    const float* __restrict__ bias, const float* __restrict__ res,
    int M, int N, int K) {
  constexpr int WN = BN / 64;              // waves along N (4 or 2)
  constexpr int TPB = WN * 128;            // threads (512 or 256)
  constexpr int ARNDS = 16384 / (TPB * 16);  // A-unit rounds (2 or 4)
  constexpr int BSZ = BN * 32;             // B-unit shorts (8192 or 4096)
  constexpr int SZ = 16384 + BN * 64;      // shorts per buffer
  constexpr int CNT = (BN == 256) ? 4 : 6; // counted vmcnt
  __shared__ short lds[2][SZ];             // 128 KiB / 96 KiB

  const int tid = threadIdx.x;
  const int l = tid & 63, w = tid >> 6;
  const int wm = w / WN, wn = w % WN;
  const int nbm = M >> 8, nbn = N / BN, nwg = nbm * nbn;
  int wg = blockIdx.x;
  wg = (wg & 7) * (nwg >> 3) + (wg >> 3);  // XCD swizzle (grids %8==0)
  const int bm = wg % nbm, bn = wg / nbm;

  // staging source (pre-swizzled so linear LDS dest yields swizzled layout)
  const int lrow0 = w * 16 + (l >> 2);     // row within unit for round 0
  const int sslot = (l & 3) ^ ((lrow0 >> 1) & 3);  // constant across rounds
  const short* Asrc = A + (size_t)(bm * 256 + lrow0) * K + sslot * 8;
  const short* Bsrc = Bt + (size_t)(bn * BN + lrow0) * K + sslot * 8;

  auto stageA = [&](int u, int kh, short* bufb) {
    short* d = bufb + kh * 8192 + w * 512;
    const short* s = Asrc + (size_t)u * 64 + kh * 32;
#pragma unroll
    for (int j = 0; j < ARNDS; ++j)
      gload16(s + (size_t)j * (TPB / 4) * K, d + j * TPB * 8);
  };
  auto stageB = [&](int u, int kh, short* bufb) {
    short* d = bufb + 16384 + kh * BSZ + w * 512;
    const short* s = Bsrc + (size_t)u * 64 + kh * 32;
#pragma unroll
    for (int j = 0; j < 2; ++j)
      gload16(s + (size_t)j * (TPB / 4) * K, d + j * TPB * 8);
  };

  // fragment offsets (shorts): row r of 32 shorts, slot = fg4 ^ ((r>>1)&3) -> 2-way max
  const int fr = l & 15, fg4 = l >> 4;
  int aoffs[8], boffs[4];
#pragma unroll
  for (int mi = 0; mi < 8; ++mi) {
    const int r = wm * 128 + mi * 16 + fr;
    aoffs[mi] = r * 32 + ((fg4 ^ ((r >> 1) & 3)) << 3);
  }
#pragma unroll
  for (int q = 0; q < 4; ++q) {
    const int r = wn * 64 + (q >> 1) * 32 + (q & 1) * 16 + fr;
    boffs[q] = r * 32 + ((fg4 ^ ((r >> 1) & 3)) << 3);
  }

  f32x4 acc[8][4] = {};
  const int NT = K >> 6;

  // prologue: stage tile 0's 4 units, prove {Ak0,Bk0}
  stageA(0, 0, &lds[0][0]);
  stageB(0, 0, &lds[0][0]);
  stageA(0, 1, &lds[0][0]);
  stageB(0, 1, &lds[0][0]);
  if constexpr (BN == 256)
    asm volatile("s_waitcnt vmcnt(4)\n\ts_barrier" ::: "memory");
  else
    asm volatile("s_waitcnt vmcnt(6)\n\ts_barrier" ::: "memory");

  for (int t = 0; t < NT; ++t) {
    const short* cur = &lds[t & 1][0];
    short* nxt = &lds[(t + 1) & 1][0];
    const bool pf = (t + 1 < NT);
    bf16x8 af[8], bf0, bf1;

    // ---- phase 0: (kh=0, ch=0) ----
#pragma unroll
    for (int mi = 0; mi < 8; ++mi) af[mi] = *(const bf16x8*)(cur + aoffs[mi]);
    bf0 = *(const bf16x8*)(cur + 16384 + boffs[0]);
    bf1 = *(const bf16x8*)(cur + 16384 + boffs[1]);
    if (pf) stageA(t + 1, 0, nxt);
    asm volatile("s_barrier" ::: "memory");
    __builtin_amdgcn_s_setprio(1);
#pragma unroll
    for (int mi = 0; mi < 8; ++mi) {
      acc[mi][0] = __builtin_amdgcn_mfma_f32_16x16x32_bf16(af[mi], bf0, acc[mi][0], 0, 0, 0);
      acc[mi][1] = __builtin_amdgcn_mfma_f32_16x16x32_bf16(af[mi], bf1, acc[mi][1], 0, 0, 0);
    }
    __builtin_amdgcn_s_setprio(0);
    asm volatile("s_barrier" ::: "memory");

    // ---- phase 1: (kh=0, ch=1) ----
    bf0 = *(const bf16x8*)(cur + 16384 + boffs[2]);
    bf1 = *(const bf16x8*)(cur + 16384 + boffs[3]);
    if (pf) stageB(t + 1, 0, nxt);
    asm volatile("s_barrier" ::: "memory");
    __builtin_amdgcn_s_setprio(1);
#pragma unroll
    for (int mi = 0; mi < 8; ++mi) {
      acc[mi][2] = __builtin_amdgcn_mfma_f32_16x16x32_bf16(af[mi], bf0, acc[mi][2], 0, 0, 0);
      acc[mi][3] = __builtin_amdgcn_mfma_f32_16x16x32_bf16(af[mi], bf1, acc[mi][3], 0, 0, 0);
    }
    __builtin_amdgcn_s_setprio(0);
    if (pf) {  // prove {Ak1,Bk1}(t) landed (oldest CNT loads), keep t+1's in flight
      if constexpr (BN == 256)
        asm volatile("s_waitcnt vmcnt(4)\n\ts_barrier" ::: "memory");
      else
        asm volatile("s_waitcnt vmcnt(6)\n\ts_barrier" ::: "memory");
    } else {
      asm volatile("s_waitcnt vmcnt(0)\n\ts_barrier" ::: "memory");
    }

    // ---- phase 2: (kh=1, ch=0) ----
#pragma unroll
    for (int mi = 0; mi < 8; ++mi) af[mi] = *(const bf16x8*)(cur + 8192 + aoffs[mi]);
    bf0 = *(const bf16x8*)(cur + 16384 + BSZ + boffs[0]);
    bf1 = *(const bf16x8*)(cur + 16384 + BSZ + boffs[1]);
    if (pf) stageA(t + 1, 1, nxt);
    asm volatile("s_barrier" ::: "memory");
    __builtin_amdgcn_s_setprio(1);
#pragma unroll
    for (int mi = 0; mi < 8; ++mi) {
      acc[mi][0] = __builtin_amdgcn_mfma_f32_16x16x32_bf16(af[mi], bf0, acc[mi][0], 0, 0, 0);
      acc[mi][1] = __builtin_amdgcn_mfma_f32_16x16x32_bf16(af[mi], bf1, acc[mi][1], 0, 0, 0);
    }
    __builtin_amdgcn_s_setprio(0);
    asm volatile("s_barrier" ::: "memory");

    // ---- phase 3: (kh=1, ch=1) ----
    bf0 = *(const bf16x8*)(cur + 16384 + BSZ + boffs[2]);
    bf1 = *(const bf16x8*)(cur + 16384 + BSZ + boffs[3]);
    if (pf) stageB(t + 1, 1, nxt);
    asm volatile("s_barrier" ::: "memory");
    __builtin_amdgcn_s_setprio(1);
#pragma unroll
    for (int mi = 0; mi < 8; ++mi) {
      acc[mi][2] = __builtin_amdgcn_mfma_f32_16x16x32_bf16(af[mi], bf0, acc[mi][2], 0, 0, 0);
      acc[mi][3] = __builtin_amdgcn_mfma_f32_16x16x32_bf16(af[mi], bf1, acc[mi][3], 0, 0, 0);
    }
    __builtin_amdgcn_s_setprio(0);
    if (pf) {  // prove {Ak0,Bk0}(t+1) landed before next iter reads them
      if constexpr (BN == 256)
        asm volatile("s_waitcnt vmcnt(4)\n\ts_barrier" ::: "memory");
      else
        asm volatile("s_waitcnt vmcnt(6)\n\ts_barrier" ::: "memory");
    }
  }

  // epilogue
  const int fq = (l >> 4) * 4;
  const int wrb = bm * 256 + wm * 128;
  const int wcb = bn * BN + wn * 64;
#pragma unroll
  for (int mi = 0; mi < 8; ++mi) {
#pragma unroll
    for (int ni = 0; ni < 4; ++ni) {
#pragma unroll
      for (int rr = 0; rr < 4; ++rr) {
        const int row = wrb + mi * 16 + fq + rr;
        const int col = wcb + ni * 16 + fr;
        float v = acc[mi][ni][rr];
        if (EPI == 0) {
          Cb[(size_t)row * N + col] = f2b(v);
        } else if (EPI == 1) {
          Cf[(size_t)row * N + col] = v + res[(size_t)row * N + col];
        } else if (EPI == 2) {
          v += bias[col];
          v = 0.5f * v * (1.0f + erff(v * 0.70710678118f));
          Cb[(size_t)row * N + col] = f2b(v);
        } else {
          Cf[(size_t)row * N + col] = v + bias[col] + res[(size_t)row * N + col];
        }
      }
    }
  }
}

// ======= Flash attention (causal), swapped-operand 32x32 MFMA, in-register softmax =======
__global__ __launch_bounds__(256, 2) void attn_kernel(
    const short* __restrict__ qkv, const short* __restrict__ vt, short* __restrict__ ctx) {
  __shared__ short Kls[2][64 * 64];   // [key][d], XOR-swizzled, double-buffered
  __shared__ short Vls[2][64 * 64];   // [d][key] (V^T tile), XOR-swizzled

  const int bid = blockIdx.x;
  const int bh = (bid & 7) * 8 + ((bid >> 3) & 7);  // XCD-colocated heads
  const int cp = bid >> 6;                          // chunk pair 0..7
  const int bb = bh >> 4, hh = bh & 15;
  const int lane = threadIdx.x & 63, wave = threadIdx.x >> 6;
  const int ql = lane & 31, hi = lane >> 5;
  const int qbA = cp * 128 + wave * 32;
  const int qbB = (15 - cp) * 128 + wave * 32;

  bf16x8 qf[2][4];
#pragma unroll
  for (int hf = 0; hf < 2; ++hf) {
    const int qb0 = hf ? qbB : qbA;
    const size_t qrow = ((size_t)bb * NS + qb0 + ql) * QKS + hh * NHD;
#pragma unroll
    for (int st = 0; st < 4; ++st)
      qf[hf][st] = *(const bf16x8*)&qkv[qrow + st * 16 + hi * 8];
  }

  f32x16 acc[2][2] = {};
  float m_run[2] = {-1e37f, -1e37f};
  float l_run[2] = {0.f, 0.f};

  const int srow = lane >> 3;
  const int sslot = (lane & 7) ^ srow;
  const short* kbasep = qkv + (size_t)bb * NS * QKS + 1024 + hh * NHD + sslot * 8;
  const short* vbasep = vt + (size_t)bh * NHD * NS + sslot * 8;

  const int nkt = (16 - cp) * 2;
#pragma unroll
  for (int r = 0; r < 2; ++r) {
    const int row = r * 32 + wave * 8 + srow;
    gload16(kbasep + (size_t)row * QKS, &Kls[0][(r * 32 + wave * 8) * 64]);
    gload16(vbasep + (size_t)row * NS, &Vls[0][(r * 32 + wave * 8) * 64]);
  }

  int buf = 0;
  for (int jt = 0; jt < nkt; ++jt) {
    asm volatile("s_waitcnt vmcnt(0)\n\ts_barrier" ::: "memory");
    if (jt + 1 < nkt) {
      const int k0n = (jt + 1) * 64;
#pragma unroll
      for (int r = 0; r < 2; ++r) {
        const int row = r * 32 + wave * 8 + srow;
        gload16(kbasep + (size_t)(k0n + row) * QKS, &Kls[buf ^ 1][(r * 32 + wave * 8) * 64]);
        gload16(vbasep + (size_t)row * NS + k0n, &Vls[buf ^ 1][(r * 32 + wave * 8) * 64]);
      }
    }
    const int k0 = jt * 64;
    const short* Kb = &Kls[buf][0];
    const short* Vb = &Vls[buf][0];
#pragma unroll
    for (int ks = 0; ks < 2; ++ks) {
      const int kbase = k0 + ks * 32;
      if (kbase > qbB) continue;
      bf16x8 kf[4], vf[2][2];
      const int krow = ks * 32 + ql;
#pragma unroll
      for (int st = 0; st < 4; ++st)
        kf[st] = *(const bf16x8*)&Kb[krow * 64 + ((st * 2 + hi) ^ (krow & 7)) * 8];
#pragma unroll
      for (int db = 0; db < 2; ++db) {
        const int vrow = db * 32 + ql;
#pragma unroll
        for (int su = 0; su < 2; ++su)
          vf[db][su] =
              *(const bf16x8*)&Vb[vrow * 64 + ((ks * 4 + su * 2 + hi) ^ (vrow & 7)) * 8];
      }
#pragma unroll
      for (int hf = 0; hf < 2; ++hf) {
        const int qb0 = hf ? qbB : qbA;
        if (kbase > qb0) continue;
        const int qg = qb0 + ql;
        f32x16 s = {};
        __builtin_amdgcn_s_setprio(1);
#pragma unroll
        for (int st = 0; st < 4; ++st)
          s = __builtin_amdgcn_mfma_f32_32x32x16_bf16(kf[st], qf[hf][st], s, 0, 0, 0);
        __builtin_amdgcn_s_setprio(0);
        const bool masked = (kbase + 31 > qb0);
        float pv[16];
        float mt = -INFINITY;
#pragma unroll
        for (int r = 0; r < 16; ++r) {
          float v = s[r] * 0.125f;
          if (masked) {
            const int key = kbase + 4 * hi + (r & 3) + 8 * (r >> 2);
            v = (key > qg) ? -INFINITY : v;
          }
          pv[r] = v;
          mt = fmaxf(mt, v);
        }
        mt = pairmax(mt);
        if (!__all(mt - m_run[hf] <= 8.0f)) {
          const float mn = fmaxf(m_run[hf], mt);
          const float sc = __expf(m_run[hf] - mn);
          m_run[hf] = mn;
          l_run[hf] *= sc;
          acc[hf][0] *= sc;
          acc[hf][1] *= sc;
        }
        float pe[16];
        float lt = 0.f;
#pragma unroll
        for (int r = 0; r < 16; ++r) {
          pe[r] = __expf(fminf(pv[r] - m_run[hf], 80.0f));
          lt += pe[r];
        }
        l_run[hf] += pairsum(lt);
        bf16x8 pf[2];
#pragma unroll
        for (int su = 0; su < 2; ++su) {
          const int a0 = cvtpk(pe[su * 8 + 0], pe[su * 8 + 1]);
          const int a1 = cvtpk(pe[su * 8 + 2], pe[su * 8 + 3]);
          const int b0 = cvtpk(pe[su * 8 + 4], pe[su * 8 + 5]);
          const int b1 = cvtpk(pe[su * 8 + 6], pe[su * 8 + 7]);
          auto r0 = __builtin_amdgcn_permlane32_swap((unsigned)a0, (unsigned)b0, false, false);
          auto r1 = __builtin_amdgcn_permlane32_swap((unsigned)a1, (unsigned)b1, false, false);
          union { i32x4 w; bf16x8 v; } u;
          u.w[0] = r0[0]; u.w[1] = r1[0]; u.w[2] = r0[1]; u.w[3] = r1[1];
          pf[su] = u.v;
        }
        __builtin_amdgcn_s_setprio(1);
#pragma unroll
        for (int su = 0; su < 2; ++su) {
          acc[hf][0] = __builtin_amdgcn_mfma_f32_32x32x16_bf16(vf[0][su], pf[su], acc[hf][0], 0, 0, 0);
          acc[hf][1] = __builtin_amdgcn_mfma_f32_32x32x16_bf16(vf[1][su], pf[su], acc[hf][1], 0, 0, 0);
        }
        __builtin_amdgcn_s_setprio(0);
      }
    }
    asm volatile("s_waitcnt lgkmcnt(0)\n\ts_barrier" ::: "memory");
    buf ^= 1;
  }

#pragma unroll
  for (int hf = 0; hf < 2; ++hf) {
    const int qb0 = hf ? qbB : qbA;
    const float inv = 1.0f / l_run[hf];
    const size_t ob = ((size_t)bb * NS + qb0 + ql) * ND + hh * NHD + hi * 8;
#pragma unroll
    for (int db = 0; db < 2; ++db) {
#pragma unroll
      for (int J = 0; J < 2; ++J) {
        const int a0 = cvtpk(acc[hf][db][J * 8 + 0] * inv, acc[hf][db][J * 8 + 1] * inv);
        const int a1 = cvtpk(acc[hf][db][J * 8 + 2] * inv, acc[hf][db][J * 8 + 3] * inv);
        const int b0 = cvtpk(acc[hf][db][J * 8 + 4] * inv, acc[hf][db][J * 8 + 5] * inv);
        const int b1 = cvtpk(acc[hf][db][J * 8 + 6] * inv, acc[hf][db][J * 8 + 7] * inv);
        auto r0 = __builtin_amdgcn_permlane32_swap((unsigned)a0, (unsigned)b0, false, false);
        auto r1 = __builtin_amdgcn_permlane32_swap((unsigned)a1, (unsigned)b1, false, false);
        union { i32x4 w; bf16x8 v; } u;
        u.w[0] = r0[0]; u.w[1] = r1[0]; u.w[2] = r0[1]; u.w[3] = r1[1];
        *(bf16x8*)&ctx[ob + db * 32 + J * 16] = u.v;
      }
    }
  }
}

extern "C" void kernel_launch(void* const* d_in, const int* in_sizes, int n_in,
                              void* d_out, int out_size, void* d_ws, size_t ws_size,
                              hipStream_t stream) {
  (void)in_sizes; (void)n_in; (void)out_size; (void)ws_size;
  const float* x     = (const float*)d_in[0];
  const float* ln1_g = (const float*)d_in[1];
  const float* ln1_b = (const float*)d_in[2];
  const float* Wq    = (const float*)d_in[3];
  const float* Wk    = (const float*)d_in[4];
  const float* Wv    = (const float*)d_in[5];
  const float* Wo    = (const float*)d_in[6];
  const float* ln2_g = (const float*)d_in[7];
  const float* ln2_b = (const float*)d_in[8];
  const float* W1    = (const float*)d_in[9];
  const float* b1    = (const float*)d_in[10];
  const float* W2    = (const float*)d_in[11];
  const float* b2    = (const float*)d_in[12];
  float* out = (float*)d_out;

  char* ws = (char*)d_ws;
  const size_t MiB = 1024 * 1024;
  short* wqkvT = (short*)(ws + 0 * MiB);   // 6 MiB: [3072][1024] packed q|k|v
  short* woT   = (short*)(ws + 6 * MiB);   // 2 MiB
  short* w1T   = (short*)(ws + 8 * MiB);   // 8 MiB
  short* w2T   = (short*)(ws + 16 * MiB);  // 8 MiB
  short* h     = (short*)(ws + 24 * MiB);  // 16 MiB: LN out; ctx reuses after h dead
  short* ctx   = (short*)(ws + 24 * MiB);
  short* qkv   = (short*)(ws + 40 * MiB);  // 48 MiB: [8192][3072]
  short* vt    = (short*)(ws + 88 * MiB);  // 16 MiB: V^T [64][64][2048]
  short* hff   = (short*)(ws + 40 * MiB);  // 64 MiB: reuses qkv+vt after attention
  float* x1    = (float*)(ws + 104 * MiB); // 32 MiB; end = 136 MiB

  tcast_kernel<<<dim3(32, 32), 256, 0, stream>>>(Wq, wqkvT, 1024, 1024);
  tcast_kernel<<<dim3(32, 32), 256, 0, stream>>>(Wk, wqkvT + 1024 * 1024, 1024, 1024);
  tcast_kernel<<<dim3(32, 32), 256, 0, stream>>>(Wv, wqkvT + 2048 * 1024, 1024, 1024);
  tcast_kernel<<<dim3(32, 32), 256, 0, stream>>>(Wo, woT, 1024, 1024);
  tcast_kernel<<<dim3(128, 32), 256, 0, stream>>>(W1, w1T, 1024, 4096);
  tcast_kernel<<<dim3(32, 128), 256, 0, stream>>>(W2, w2T, 4096, 1024);

  // LN1
  ln_kernel<<<8192, 256, 0, stream>>>(x, ln1_g, ln1_b, h);

  // fused QKV projection: [8192][3072]
  gemmp_kernel<256, 0><<<384, 512, 0, stream>>>(h, wqkvT, nullptr, qkv, nullptr, nullptr,
                                                8192, 3072, 1024);
  vtrans_kernel<<<dim3(32, 64), 256, 0, stream>>>(qkv, vt);

  // causal flash attention
  attn_kernel<<<512, 256, 0, stream>>>(qkv, vt, ctx);

  // out-proj + residual -> x1 (f32)
  gemmp_kernel<128, 1><<<256, 256, 0, stream>>>(ctx, woT, x1, nullptr, nullptr, x,
                                                8192, 1024, 1024);

  // LN2
  ln_kernel<<<8192, 256, 0, stream>>>(x1, ln2_g, ln2_b, h);

  // FFN
  gemmp_kernel<256, 2><<<512, 512, 0, stream>>>(h, w1T, nullptr, hff, b1, nullptr,
                                                8192, 4096, 1024);
  gemmp_kernel<128, 3><<<256, 256, 0, stream>>>(hff, w2T, out, nullptr, b2, x1,
                                                8192, 1024, 4096);
}

// Round 8
// 387.933 us; speedup vs baseline: 1.1483x; 1.1483x over previous
//
#include <hip/hip_runtime.h>
#include <hip/hip_bf16.h>
#include <math.h>

#define NB 4
#define NS 2048
#define ND 1024
#define NH 16
#define NHD 64
#define NDFF 4096
#define QKS 3072   // packed qkv row stride

typedef __attribute__((ext_vector_type(8))) short bf16x8;
typedef __attribute__((ext_vector_type(4))) float f32x4;
typedef __attribute__((ext_vector_type(16))) float f32x16;
typedef __attribute__((ext_vector_type(4))) short short4v;
typedef __attribute__((ext_vector_type(4))) int i32x4;

static __device__ __forceinline__ short f2b(float f) {
  union { __hip_bfloat16 b; short s; } u;
  u.b = __float2bfloat16(f);
  return u.s;
}

static __device__ __forceinline__ int cvtpk(float lo, float hi_) {
  int r;
  asm("v_cvt_pk_bf16_f32 %0, %1, %2" : "=v"(r) : "v"(lo), "v"(hi_));
  return r;
}

static __device__ __forceinline__ float pairmax(float x) {
  auto r = __builtin_amdgcn_permlane32_swap(__float_as_uint(x), __float_as_uint(x), false, false);
  return fmaxf(__uint_as_float(r[0]), __uint_as_float(r[1]));
}
static __device__ __forceinline__ float pairsum(float x) {
  auto r = __builtin_amdgcn_permlane32_swap(__float_as_uint(x), __float_as_uint(x), false, false);
  return __uint_as_float(r[0]) + __uint_as_float(r[1]);
}

// ---------------- LayerNorm: f32 in -> bf16 out ----------------
__global__ __launch_bounds__(256) void ln_kernel(
    const float* __restrict__ x, const float* __restrict__ g,
    const float* __restrict__ b, short* __restrict__ out) {
  __shared__ float red[8];
  const int row = blockIdx.x;
  const int t = threadIdx.x;
  const float* xr = x + (size_t)row * ND;
  const float4 xv = *(const float4*)(xr + t * 4);
  float s = xv.x + xv.y + xv.z + xv.w;
  float ss = xv.x * xv.x + xv.y * xv.y + xv.z * xv.z + xv.w * xv.w;
#pragma unroll
  for (int m = 32; m >= 1; m >>= 1) {
    s += __shfl_xor(s, m);
    ss += __shfl_xor(ss, m);
  }
  if ((t & 63) == 0) { red[(t >> 6) * 2] = s; red[(t >> 6) * 2 + 1] = ss; }
  __syncthreads();
  s = red[0] + red[2] + red[4] + red[6];
  ss = red[1] + red[3] + red[5] + red[7];
  const float mu = s * (1.0f / ND);
  const float var = ss * (1.0f / ND) - mu * mu;
  const float rs = rsqrtf(var + 1e-5f);
  const float4 gv = *(const float4*)(g + t * 4);
  const float4 bv = *(const float4*)(b + t * 4);
  short o[4];
  o[0] = f2b((xv.x - mu) * rs * gv.x + bv.x);
  o[1] = f2b((xv.y - mu) * rs * gv.y + bv.y);
  o[2] = f2b((xv.z - mu) * rs * gv.z + bv.z);
  o[3] = f2b((xv.w - mu) * rs * gv.w + bv.w);
  *(short4v*)(out + (size_t)row * ND + t * 4) = *(short4v*)o;
}

// ------------- transpose + cast: in f32 (K x N) -> out bf16 (N x K) -------------
__global__ __launch_bounds__(256) void tcast_kernel(
    const float* __restrict__ in, short* __restrict__ out, int K, int N) {
  __shared__ float tile[32][33];
  const int n0 = blockIdx.x * 32, k0 = blockIdx.y * 32;
  const int tx = threadIdx.x & 31, ty = threadIdx.x >> 5;  // 32 x 8
#pragma unroll
  for (int i = 0; i < 32; i += 8)
    tile[ty + i][tx] = in[(size_t)(k0 + ty + i) * N + n0 + tx];
  __syncthreads();
#pragma unroll
  for (int i = 0; i < 32; i += 8)
    out[(size_t)(n0 + ty + i) * K + k0 + tx] = f2b(tile[tx][ty + i]);
}

// ------------- V transpose: packed qkv (v at col 2048) -> vt[b*H+h][d][s] bf16 -------------
__global__ __launch_bounds__(256) void vtrans_kernel(
    const short* __restrict__ in, short* __restrict__ out) {
  __shared__ short tile[64][72];
  const int s0 = blockIdx.x * 64, bh = blockIdx.y;
  const int bb = bh >> 4, hh = bh & 15;
  const int rr = threadIdx.x >> 3, cc = (threadIdx.x & 7) * 8;  // rr 0..31
#pragma unroll
  for (int it = 0; it < 2; ++it) {
    const int r = rr + it * 32;
    *(bf16x8*)&tile[r][cc] =
        *(const bf16x8*)&in[((size_t)(bb * NS + s0 + r)) * QKS + 2048 + hh * NHD + cc];
  }
  __syncthreads();
  const size_t ob = (size_t)bh * NHD * NS;
#pragma unroll
  for (int it = 0; it < 2; ++it) {
    const int d = rr + it * 32;
    short o[8];
#pragma unroll
    for (int j = 0; j < 8; ++j) o[j] = tile[cc + j][d];
    *(bf16x8*)&out[ob + (size_t)d * NS + s0 + cc] = *(bf16x8*)o;
  }
}

__device__ __forceinline__ void gload16(const void* g, void* l) {
  __builtin_amdgcn_global_load_lds(
      (const __attribute__((address_space(1))) unsigned int*)g,
      (__attribute__((address_space(3))) unsigned int*)l, 16, 0, 0);
}

// ======== ring-4 deep-pipeline GEMM: C(256 x BN) = A(MxK) * Bt(NxK)^T + epilogue ========
// 512 threads / 8 waves. BK=32 tiles; 4-slot LDS ring; stage tile t+3 during tile t;
// one counted vmcnt per tile proving tile t+1 (issued 3 tiles earlier -> ~1000cy cover).
// BN=256: waves 2Mx4N (wave 128x64), 2 phases/tile. BN=128: waves 4Mx2N (64x64), 1 phase.
// Swizzle: LDS[r][s] = global[r][s ^ ((r>>1)&3)] (16B slots) -> 2-way max on ds_read_b128.
// EPI: 0 = plain -> bf16; 1 = +res -> f32; 2 = +bias,gelu -> bf16; 3 = +bias+res -> f32
template <int BN, int EPI>
__global__ __launch_bounds__(512, 2) void gemmr_kernel(
    const short* __restrict__ A, const short* __restrict__ Bt,
    float* __restrict__ Cf, short* __restrict__ Cb,
    const float* __restrict__ bias, const float* __restrict__ res,
    int M, int N, int K) {
  constexpr int MI = (BN == 256) ? 8 : 4;     // m-frags per wave
  constexpr int NWN = (BN == 256) ? 4 : 2;    // waves along N
  constexpr int ABUF = 8192;                  // shorts: A 256x32
  constexpr int TS = ABUF + BN * 32;          // shorts per ring slot
  __shared__ short lds[4][TS];                // 128 KiB / 96 KiB

  const int tid = threadIdx.x, l = tid & 63, w = tid >> 6;
  const int wm = w / NWN, wn = w % NWN;
  const int nbm = M >> 8, nbn = N / BN, nwg = nbm * nbn;
  int wg = blockIdx.x;
  wg = (wg & 7) * (nwg >> 3) + (wg >> 3);     // XCD swizzle (grids %8==0)
  const int bm = wg / nbn, bn = wg % nbn;     // bn-inner: A-panel L2 reuse within chunk

  // staging: linear LDS dest (w*512 + lane*8 shorts), pre-swizzled global source
  const int lrow = tid >> 2;                  // 0..127
  const int sslot = (l & 3) ^ ((lrow >> 1) & 3);
  const short* Asrc = A + (size_t)(bm * 256 + lrow) * K + sslot * 8;
  const short* Bsrc = Bt + (size_t)(bn * BN + lrow) * K + sslot * 8;
  const int ldst = w * 512;

  // fragment offsets: row r -> slot fg4 ^ ((r>>1)&3); 2-way bank conflicts max
  const int fr = l & 15, fg4 = l >> 4;
  int aoff[MI], boff[4];
#pragma unroll
  for (int mi = 0; mi < MI; ++mi) {
    const int r = wm * (MI * 16) + mi * 16 + fr;
    aoff[mi] = r * 32 + ((fg4 ^ ((r >> 1) & 3)) << 3);
  }
#pragma unroll
  for (int nj = 0; nj < 4; ++nj) {
    const int r = wn * 64 + nj * 16 + fr;
    boff[nj] = ABUF + r * 32 + ((fg4 ^ ((r >> 1) & 3)) << 3);
  }

  auto stageAB = [&](int t, short* buf) {
    const short* sa = Asrc + t * 32;
    gload16(sa, buf + ldst);
    gload16(sa + (size_t)128 * K, buf + 4096 + ldst);
    const short* sb = Bsrc + t * 32;
    gload16(sb, buf + ABUF + ldst);
    if constexpr (BN == 256) gload16(sb + (size_t)128 * K, buf + ABUF + 4096 + ldst);
  };

  f32x4 acc[MI][4] = {};
  const int NT = K >> 5;

  // prologue: stage tiles 0,1,2; prove tile 0 (leave 2*LPT in flight)
  stageAB(0, lds[0]);
  stageAB(1, lds[1]);
  stageAB(2, lds[2]);
  if constexpr (BN == 256)
    asm volatile("s_waitcnt vmcnt(8)\n\ts_barrier" ::: "memory");
  else
    asm volatile("s_waitcnt vmcnt(6)\n\ts_barrier" ::: "memory");

  for (int t = 0; t < NT; ++t) {
    const short* cur = &lds[t & 3][0];
    short* pbuf = &lds[(t + 3) & 3][0];   // == slot (t-1)%4: dead since entry barrier
    const bool st = (t + 3 < NT);
    bf16x8 bfr[4], af[4];
    // ---- phase 0: m-half 0 ----
#pragma unroll
    for (int nj = 0; nj < 4; ++nj) bfr[nj] = *(const bf16x8*)(cur + boff[nj]);
#pragma unroll
    for (int mi = 0; mi < 4; ++mi) af[mi] = *(const bf16x8*)(cur + aoff[mi]);
    if (st) stageAB(t + 3, pbuf);
    asm volatile("s_barrier" ::: "memory");
    __builtin_amdgcn_s_setprio(1);
#pragma unroll
    for (int mi = 0; mi < 4; ++mi)
#pragma unroll
      for (int nj = 0; nj < 4; ++nj)
        acc[mi][nj] = __builtin_amdgcn_mfma_f32_16x16x32_bf16(af[mi], bfr[nj], acc[mi][nj], 0, 0, 0);
    __builtin_amdgcn_s_setprio(0);
    if constexpr (BN == 256) {
      // ---- phase 1: m-half 1 (B-frags reused from registers) ----
      asm volatile("s_barrier" ::: "memory");
#pragma unroll
      for (int mi = 0; mi < 4; ++mi) af[mi] = *(const bf16x8*)(cur + aoff[4 + mi]);
      asm volatile("s_barrier" ::: "memory");
      __builtin_amdgcn_s_setprio(1);
#pragma unroll
      for (int mi = 0; mi < 4; ++mi)
#pragma unroll
        for (int nj = 0; nj < 4; ++nj)
          acc[4 + mi][nj] =
              __builtin_amdgcn_mfma_f32_16x16x32_bf16(af[mi], bfr[nj], acc[4 + mi][nj], 0, 0, 0);
      __builtin_amdgcn_s_setprio(0);
    }
    // ---- tile boundary: counted proof of tile t+1 ----
    if (t + 3 < NT) {
      if constexpr (BN == 256)
        asm volatile("s_waitcnt vmcnt(8)\n\ts_barrier" ::: "memory");
      else
        asm volatile("s_waitcnt vmcnt(6)\n\ts_barrier" ::: "memory");
    } else if (t + 2 < NT) {
      if constexpr (BN == 256)
        asm volatile("s_waitcnt vmcnt(4)\n\ts_barrier" ::: "memory");
      else
        asm volatile("s_waitcnt vmcnt(3)\n\ts_barrier" ::: "memory");
    } else if (t + 1 < NT) {
      asm volatile("s_waitcnt vmcnt(0)\n\ts_barrier" ::: "memory");
    }
  }

  // epilogue
  const int fq = (l >> 4) * 4;
  const int wrb = bm * 256 + wm * (MI * 16);
  const int wcb = bn * BN + wn * 64;
#pragma unroll
  for (int mi = 0; mi < MI; ++mi) {
#pragma unroll
    for (int ni = 0; ni < 4; ++ni) {
#pragma unroll
      for (int rr = 0; rr < 4; ++rr) {
        const int row = wrb + mi * 16 + fq + rr;
        const int col = wcb + ni * 16 + fr;
        float v = acc[mi][ni][rr];
        if (EPI == 0) {
          Cb[(size_t)row * N + col] = f2b(v);
        } else if (EPI == 1) {
          Cf[(size_t)row * N + col] = v + res[(size_t)row * N + col];
        } else if (EPI == 2) {
          v += bias[col];
          v = 0.5f * v * (1.0f + erff(v * 0.70710678118f));
          Cb[(size_t)row * N + col] = f2b(v);
        } else {
          Cf[(size_t)row * N + col] = v + bias[col] + res[(size_t)row * N + col];
        }
      }
    }
  }
}

// ======= Flash attention (causal), swapped-operand 32x32 MFMA, in-register softmax =======
__global__ __launch_bounds__(256, 2) void attn_kernel(
    const short* __restrict__ qkv, const short* __restrict__ vt, short* __restrict__ ctx) {
  __shared__ short Kls[2][64 * 64];   // [key][d], XOR-swizzled, double-buffered
  __shared__ short Vls[2][64 * 64];   // [d][key] (V^T tile), XOR-swizzled

  const int bid = blockIdx.x;
  const int bh = (bid & 7) * 8 + ((bid >> 3) & 7);  // XCD-colocated heads
  const int cp = bid >> 6;                          // chunk pair 0..7
  const int bb = bh >> 4, hh = bh & 15;
  const int lane = threadIdx.x & 63, wave = threadIdx.x >> 6;
  const int ql = lane & 31, hi = lane >> 5;
  const int qbA = cp * 128 + wave * 32;
  const int qbB = (15 - cp) * 128 + wave * 32;

  bf16x8 qf[2][4];
#pragma unroll
  for (int hf = 0; hf < 2; ++hf) {
    const int qb0 = hf ? qbB : qbA;
    const size_t qrow = ((size_t)bb * NS + qb0 + ql) * QKS + hh * NHD;
#pragma unroll
    for (int st = 0; st < 4; ++st)
      qf[hf][st] = *(const bf16x8*)&qkv[qrow + st * 16 + hi * 8];
  }

  f32x16 acc[2][2] = {};
  float m_run[2] = {-1e37f, -1e37f};
  float l_run[2] = {0.f, 0.f};

  const int srow = lane >> 3;
  const int sslot = (lane & 7) ^ srow;
  const short* kbasep = qkv + (size_t)bb * NS * QKS + 1024 + hh * NHD + sslot * 8;
  const short* vbasep = vt + (size_t)bh * NHD * NS + sslot * 8;

  const int nkt = (16 - cp) * 2;
#pragma unroll
  for (int r = 0; r < 2; ++r) {
    const int row = r * 32 + wave * 8 + srow;
    gload16(kbasep + (size_t)row * QKS, &Kls[0][(r * 32 + wave * 8) * 64]);
    gload16(vbasep + (size_t)row * NS, &Vls[0][(r * 32 + wave * 8) * 64]);
  }

  int buf = 0;
  for (int jt = 0; jt < nkt; ++jt) {
    asm volatile("s_waitcnt vmcnt(0)\n\ts_barrier" ::: "memory");
    if (jt + 1 < nkt) {
      const int k0n = (jt + 1) * 64;
#pragma unroll
      for (int r = 0; r < 2; ++r) {
        const int row = r * 32 + wave * 8 + srow;
        gload16(kbasep + (size_t)(k0n + row) * QKS, &Kls[buf ^ 1][(r * 32 + wave * 8) * 64]);
        gload16(vbasep + (size_t)row * NS + k0n, &Vls[buf ^ 1][(r * 32 + wave * 8) * 64]);
      }
    }
    const int k0 = jt * 64;
    const short* Kb = &Kls[buf][0];
    const short* Vb = &Vls[buf][0];
#pragma unroll
    for (int ks = 0; ks < 2; ++ks) {
      const int kbase = k0 + ks * 32;
      if (kbase > qbB) continue;
      bf16x8 kf[4], vf[2][2];
      const int krow = ks * 32 + ql;
#pragma unroll
      for (int st = 0; st < 4; ++st)
        kf[st] = *(const bf16x8*)&Kb[krow * 64 + ((st * 2 + hi) ^ (krow & 7)) * 8];
#pragma unroll
      for (int db = 0; db < 2; ++db) {
        const int vrow = db * 32 + ql;
#pragma unroll
        for (int su = 0; su < 2; ++su)
          vf[db][su] =
              *(const bf16x8*)&Vb[vrow * 64 + ((ks * 4 + su * 2 + hi) ^ (vrow & 7)) * 8];
      }
#pragma unroll
      for (int hf = 0; hf < 2; ++hf) {
        const int qb0 = hf ? qbB : qbA;
        if (kbase > qb0) continue;
        const int qg = qb0 + ql;
        f32x16 s = {};
        __builtin_amdgcn_s_setprio(1);
#pragma unroll
        for (int st = 0; st < 4; ++st)
          s = __builtin_amdgcn_mfma_f32_32x32x16_bf16(kf[st], qf[hf][st], s, 0, 0, 0);
        __builtin_amdgcn_s_setprio(0);
        const bool masked = (kbase + 31 > qb0);
        float pv[16];
        float mt = -INFINITY;
#pragma unroll
        for (int r = 0; r < 16; ++r) {
          float v = s[r] * 0.125f;
          if (masked) {
            const int key = kbase + 4 * hi + (r & 3) + 8 * (r >> 2);
            v = (key > qg) ? -INFINITY : v;
          }
          pv[r] = v;
          mt = fmaxf(mt, v);
        }
        mt = pairmax(mt);
        if (!__all(mt - m_run[hf] <= 8.0f)) {
          const float mn = fmaxf(m_run[hf], mt);
          const float sc = __expf(m_run[hf] - mn);
          m_run[hf] = mn;
          l_run[hf] *= sc;
          acc[hf][0] *= sc;
          acc[hf][1] *= sc;
        }
        float pe[16];
        float lt = 0.f;
#pragma unroll
        for (int r = 0; r < 16; ++r) {
          pe[r] = __expf(fminf(pv[r] - m_run[hf], 80.0f));
          lt += pe[r];
        }
        l_run[hf] += pairsum(lt);
        bf16x8 pf[2];
#pragma unroll
        for (int su = 0; su < 2; ++su) {
          const int a0 = cvtpk(pe[su * 8 + 0], pe[su * 8 + 1]);
          const int a1 = cvtpk(pe[su * 8 + 2], pe[su * 8 + 3]);
          const int b0 = cvtpk(pe[su * 8 + 4], pe[su * 8 + 5]);
          const int b1 = cvtpk(pe[su * 8 + 6], pe[su * 8 + 7]);
          auto r0 = __builtin_amdgcn_permlane32_swap((unsigned)a0, (unsigned)b0, false, false);
          auto r1 = __builtin_amdgcn_permlane32_swap((unsigned)a1, (unsigned)b1, false, false);
          union { i32x4 w; bf16x8 v; } u;
          u.w[0] = r0[0]; u.w[1] = r1[0]; u.w[2] = r0[1]; u.w[3] = r1[1];
          pf[su] = u.v;
        }
        __builtin_amdgcn_s_setprio(1);
#pragma unroll
        for (int su = 0; su < 2; ++su) {
          acc[hf][0] = __builtin_amdgcn_mfma_f32_32x32x16_bf16(vf[0][su], pf[su], acc[hf][0], 0, 0, 0);
          acc[hf][1] = __builtin_amdgcn_mfma_f32_32x32x16_bf16(vf[1][su], pf[su], acc[hf][1], 0, 0, 0);
        }
        __builtin_amdgcn_s_setprio(0);
      }
    }
    asm volatile("s_waitcnt lgkmcnt(0)\n\ts_barrier" ::: "memory");
    buf ^= 1;
  }

#pragma unroll
  for (int hf = 0; hf < 2; ++hf) {
    const int qb0 = hf ? qbB : qbA;
    const float inv = 1.0f / l_run[hf];
    const size_t ob = ((size_t)bb * NS + qb0 + ql) * ND + hh * NHD + hi * 8;
#pragma unroll
    for (int db = 0; db < 2; ++db) {
#pragma unroll
      for (int J = 0; J < 2; ++J) {
        const int a0 = cvtpk(acc[hf][db][J * 8 + 0] * inv, acc[hf][db][J * 8 + 1] * inv);
        const int a1 = cvtpk(acc[hf][db][J * 8 + 2] * inv, acc[hf][db][J * 8 + 3] * inv);
        const int b0 = cvtpk(acc[hf][db][J * 8 + 4] * inv, acc[hf][db][J * 8 + 5] * inv);
        const int b1 = cvtpk(acc[hf][db][J * 8 + 6] * inv, acc[hf][db][J * 8 + 7] * inv);
        auto r0 = __builtin_amdgcn_permlane32_swap((unsigned)a0, (unsigned)b0, false, false);
        auto r1 = __builtin_amdgcn_permlane32_swap((unsigned)a1, (unsigned)b1, false, false);
        union { i32x4 w; bf16x8 v; } u;
        u.w[0] = r0[0]; u.w[1] = r1[0]; u.w[2] = r0[1]; u.w[3] = r1[1];
        *(bf16x8*)&ctx[ob + db * 32 + J * 16] = u.v;
      }
    }
  }
}

extern "C" void kernel_launch(void* const* d_in, const int* in_sizes, int n_in,
                              void* d_out, int out_size, void* d_ws, size_t ws_size,
                              hipStream_t stream) {
  (void)in_sizes; (void)n_in; (void)out_size; (void)ws_size;
  const float* x     = (const float*)d_in[0];
  const float* ln1_g = (const float*)d_in[1];
  const float* ln1_b = (const float*)d_in[2];
  const float* Wq    = (const float*)d_in[3];
  const float* Wk    = (const float*)d_in[4];
  const float* Wv    = (const float*)d_in[5];
  const float* Wo    = (const float*)d_in[6];
  const float* ln2_g = (const float*)d_in[7];
  const float* ln2_b = (const float*)d_in[8];
  const float* W1    = (const float*)d_in[9];
  const float* b1    = (const float*)d_in[10];
  const float* W2    = (const float*)d_in[11];
  const float* b2    = (const float*)d_in[12];
  float* out = (float*)d_out;

  char* ws = (char*)d_ws;
  const size_t MiB = 1024 * 1024;
  short* wqkvT = (short*)(ws + 0 * MiB);   // 6 MiB: [3072][1024] packed q|k|v
  short* woT   = (short*)(ws + 6 * MiB);   // 2 MiB
  short* w1T   = (short*)(ws + 8 * MiB);   // 8 MiB
  short* w2T   = (short*)(ws + 16 * MiB);  // 8 MiB
  short* h     = (short*)(ws + 24 * MiB);  // 16 MiB: LN out; ctx reuses after h dead
  short* ctx   = (short*)(ws + 24 * MiB);
  short* qkv   = (short*)(ws + 40 * MiB);  // 48 MiB: [8192][3072]
  short* vt    = (short*)(ws + 88 * MiB);  // 16 MiB: V^T [64][64][2048]
  short* hff   = (short*)(ws + 40 * MiB);  // 64 MiB: reuses qkv+vt after attention
  float* x1    = (float*)(ws + 104 * MiB); // 32 MiB; end = 136 MiB

  tcast_kernel<<<dim3(32, 32), 256, 0, stream>>>(Wq, wqkvT, 1024, 1024);
  tcast_kernel<<<dim3(32, 32), 256, 0, stream>>>(Wk, wqkvT + 1024 * 1024, 1024, 1024);
  tcast_kernel<<<dim3(32, 32), 256, 0, stream>>>(Wv, wqkvT + 2048 * 1024, 1024, 1024);
  tcast_kernel<<<dim3(32, 32), 256, 0, stream>>>(Wo, woT, 1024, 1024);
  tcast_kernel<<<dim3(128, 32), 256, 0, stream>>>(W1, w1T, 1024, 4096);
  tcast_kernel<<<dim3(32, 128), 256, 0, stream>>>(W2, w2T, 4096, 1024);

  // LN1
  ln_kernel<<<8192, 256, 0, stream>>>(x, ln1_g, ln1_b, h);

  // fused QKV projection: [8192][3072] (BN=128 -> 768 blocks = 3 exact waves)
  gemmr_kernel<128, 0><<<768, 512, 0, stream>>>(h, wqkvT, nullptr, qkv, nullptr, nullptr,
                                                8192, 3072, 1024);
  vtrans_kernel<<<dim3(32, 64), 256, 0, stream>>>(qkv, vt);

  // causal flash attention
  attn_kernel<<<512, 256, 0, stream>>>(qkv, vt, ctx);

  // out-proj + residual -> x1 (f32)
  gemmr_kernel<128, 1><<<256, 512, 0, stream>>>(ctx, woT, x1, nullptr, nullptr, x,
                                                8192, 1024, 1024);

  // LN2
  ln_kernel<<<8192, 256, 0, stream>>>(x1, ln2_g, ln2_b, h);

  // FFN
  gemmr_kernel<256, 2><<<512, 512, 0, stream>>>(h, w1T, nullptr, hff, b1, nullptr,
                                                8192, 4096, 1024);
  gemmr_kernel<128, 3><<<256, 512, 0, stream>>>(hff, w2T, out, nullptr, b2, x1,
                                                8192, 1024, 4096);
}